// Round 7
// baseline (713.613 us; speedup 1.0000x reference)
//
#include <hip/hip_runtime.h>

// ConvLSTM1D fused scan for MI355X — f32 I/O, bf16 MFMA.
// Round 7: LTILE=32, 1024 blocks -> 4 blocks/CU (4 waves/SIMD) to fill the
// ~50% issue-idle seen at 2 blocks/CU; x-prefetch pointers strength-reduced
// (hoisted clamp, constant stride per step). h stored rne-bf16; gate-pair
// permuted B so each lane writes adjacent h-cols (packed b32 store); Dense(1)
// fused into the t=49 pointwise.
// Halo-tile trick: block owns j-range [j0, j0+32); recurrent conv reads h[j+1]
// only, so a right halo that starts at +49 rows and shrinks by 1 per step makes
// every block's 50-step scan fully independent (no grid sync).

#define TT 50
#define LTILE 32
#define ROWS 97    // 6 Mtiles * 16 + 1 read-halo row (max nmt = ceil(81/16) = 6)
#define HSTR 40    // h row stride (shorts); mult of 8 -> 16B-aligned ds_read_b128

typedef __attribute__((ext_vector_type(8))) short short8;
typedef __attribute__((ext_vector_type(4))) float floatx4;

__device__ __forceinline__ unsigned short f2b_rne(float f) {
  union { float f; unsigned u; } v; v.f = f;
  unsigned r = v.u + 0x7FFFu + ((v.u >> 16) & 1u);
  return (unsigned short)(r >> 16);
}
__device__ __forceinline__ unsigned short f2b_trunc(float f) {
  union { float f; unsigned u; } v; v.f = f;
  return (unsigned short)(v.u >> 16);
}
__device__ __forceinline__ float hsig(float x) {
  return __builtin_amdgcn_fmed3f(__builtin_fmaf(0.2f, x, 0.5f), 0.0f, 1.0f);
}
__device__ __forceinline__ float ftanh(float x) {
  float e = __expf(2.0f * x);
  return 1.0f - 2.0f * __builtin_amdgcn_rcpf(e + 1.0f);
}

__global__ __launch_bounds__(256, 4)
void convlstm_scan(const float* __restrict__ xs,   // x [32][50][2048][8] f32
                   const float* __restrict__ ks,   // kernel [2][8][128] f32
                   const float* __restrict__ rks,  // rec_kernel [2][32][128] f32
                   const float* __restrict__ bs,   // bias [128] f32
                   const float* __restrict__ dws,  // dense_w [32768] f32
                   float* __restrict__ acc_out) {  // [32] f32 accumulators
  __shared__ short hbH[2][ROWS * HSTR];   // h (bf16), double-buffered

  const int tid  = threadIdx.x;
  const int b    = blockIdx.x >> 5;
  const int j0   = (blockIdx.x & 31) * LTILE;
  const int wave = tid >> 6;
  const int lane = tid & 63;
  const int q    = lane >> 4;
  const int f0   = lane & 15;

  for (int e = tid; e < ROWS * HSTR; e += 256)
    ((int*)hbH)[e] = 0;

  // ---- B fragments in registers, GATE-PAIR PERMUTED columns:
  // tile n = 2g+p, col f0  <->  oc = g*32 + 2*f0 + p   (g = gate, p = pair)
  // => lane f0's two outputs per row are adjacent h-cols 2f0, 2f0+1.
  // B[k = q*8+j][tile n, col f0] = W[k][oc]; rec_kernel[k][oc], k = tap*32+c.
  short8 Bwh0[8], Bwh1[8], Bxw[8];
#pragma unroll
  for (int n = 0; n < 8; ++n) {
    const int oc = (n >> 1) * 32 + 2 * f0 + (n & 1);
    short8 th;
#pragma unroll
    for (int j = 0; j < 8; ++j)
      th[j] = (short)f2b_rne(rks[(q * 8 + j) * 128 + oc]);
    Bwh0[n] = th;
#pragma unroll
    for (int j = 0; j < 8; ++j)
      th[j] = (short)f2b_rne(rks[(32 + q * 8 + j) * 128 + oc]);
    Bwh1[n] = th;
    // x-conv B: k rows 0..7 = tap0 k_hi, 8..15 = tap1 k_hi (paired with x_hi),
    // row 16 = bias (ax carries 1.0 there), rows 17..31 = 0.
    short8 tx = {0, 0, 0, 0, 0, 0, 0, 0};
    if (q < 2) {
#pragma unroll
      for (int j = 0; j < 8; ++j)
        tx[j] = (short)f2b_rne(ks[(q * 8 + j) * 128 + oc]);
    } else if (q == 2) {
      tx[0] = (short)f2b_rne(bs[oc]);
    }
    Bxw[n] = tx;
  }

  // ax constant part: lane (q=2, elem 0) = bf16 1.0 (bias marker), else 0.
  short8 axc = {0, 0, 0, 0, 0, 0, 0, 0};
  if (q == 2) axc[0] = (short)0x3F80;

  const floatx4 zero4 = {0.0f, 0.0f, 0.0f, 0.0f};

  float cst[2][8];   // c-state, MFMA C-layout: [m-slot][p*4 + r]
#pragma unroll
  for (int s = 0; s < 2; ++s)
#pragma unroll
    for (int i = 0; i < 8; ++i) cst[s][i] = 0.0f;

  // ---- hoisted x pointers (row clamp is t-invariant); advance 16384 fl/step
  const float* xptr[2];
  floatx4 px0[2], px1[2];
#pragma unroll
  for (int s = 0; s < 2; ++s) {
    const int jr = (wave + 4 * s) * 16 + f0;
    const int jm = min(j0 + jr, 1023);
    xptr[s] = xs + (size_t)b * TT * (2048 * 8) + (size_t)(2 * jm + (q & 1)) * 8;
    px0[s] = *(const floatx4*)xptr[s];
    px1[s] = *(const floatx4*)(xptr[s] + 4);
  }

  const int maxrows = 1024 - j0;
  float part = 0.0f;                        // fused Dense(1) partial
  __syncthreads();

  for (int t = 0; t < TT; ++t) {
    const short* curH = hbH[t & 1];
    short* nxtH = hbH[(t & 1) ^ 1];
    int rows = LTILE + (TT - 1) - t;          // halo shrinks 1/step
    if (rows > maxrows) rows = maxrows;
    const int nmt = (rows + 15) >> 4;         // 2..6
    const int act0 = wave < nmt;              // wave-uniform slot guards
    const int act1 = (wave + 4) < nmt;
    const int last = (t == TT - 1);

    // 1) Front-load a-frag LDS reads (max row read = 5*16+15+1 = 96 = ROWS-1).
    short8 a0h[2], a1h[2];
#pragma unroll
    for (int s = 0; s < 2; ++s) {
      const int jr = (wave + 4 * s) * 16 + f0;
      a0h[s] = *(const short8*)&curH[jr * HSTR + q * 8];
      a1h[s] = *(const short8*)&curH[(jr + 1) * HSTR + q * 8];
    }

    // 2) Build ax (x_hi) from registers prefetched last step.
    // k = q*8+j: q0 -> hi(x[2J][j]), q1 -> hi(x[2J+1][j]), q2 -> bias marker.
    short8 ax[2];
#pragma unroll
    for (int s = 0; s < 2; ++s) {
      ax[s] = axc;
      if (q < 2) {
        floatx4 x0 = px0[s], x1 = px1[s];
#pragma unroll
        for (int jj = 0; jj < 4; ++jj) ax[s][jj] = (short)f2b_trunc(x0[jj]);
#pragma unroll
        for (int jj = 0; jj < 4; ++jj) ax[s][4 + jj] = (short)f2b_trunc(x1[jj]);
      }
    }

    // 3) Next-step x prefetch: constant-stride pointer bump (overlaps MFMA).
    if (!last) {
#pragma unroll
      for (int s = 0; s < 2; ++s) {
        xptr[s] += 2048 * 8;
        px0[s] = *(const floatx4*)xptr[s];
        px1[s] = *(const floatx4*)(xptr[s] + 4);
      }
    }

    // 4) Per-slot MFMA + pointwise.
#pragma unroll
    for (int s = 0; s < 2; ++s) {
      if (s == 0 ? !act0 : !act1) continue;
      const int m = wave + 4 * s;

      floatx4 acc[8];
      // ax first: operands in registers, C = zero4; issues while ds_reads land.
#pragma unroll
      for (int n = 0; n < 8; ++n)
        acc[n] = __builtin_amdgcn_mfma_f32_16x16x32_bf16(ax[s], Bxw[n], zero4, 0, 0, 0);
#pragma unroll
      for (int n = 0; n < 8; ++n)
        acc[n] = __builtin_amdgcn_mfma_f32_16x16x32_bf16(a0h[s], Bwh0[n], acc[n], 0, 0, 0);
#pragma unroll
      for (int n = 0; n < 8; ++n)
        acc[n] = __builtin_amdgcn_mfma_f32_16x16x32_bf16(a1h[s], Bwh1[n], acc[n], 0, 0, 0);

      // Pointwise LSTM. D[m-row = q*4+r][tile n, col f0 -> h-col 2f0 + (n&1)].
      const int jw = m * 16 + q * 4;
#pragma unroll
      for (int r = 0; r < 4; ++r) {
        float hv2[2];
#pragma unroll
        for (int p = 0; p < 2; ++p) {
          float zi = acc[0 + p][r], zf = acc[2 + p][r];
          float zc = acc[4 + p][r], zo = acc[6 + p][r];
          float ig = hsig(zi), fg = hsig(zf), og = hsig(zo);
          float cs = cst[s][p * 4 + r];
          float cn = __builtin_fmaf(fg, cs, ig * ftanh(zc));
          cst[s][p * 4 + r] = cn;
          hv2[p] = og * ftanh(cn);
        }
        if (!last) {
          unsigned pk = (unsigned)f2b_rne(hv2[0]) |
                        ((unsigned)f2b_rne(hv2[1]) << 16);
          *(unsigned*)&nxtH[(jw + r) * HSTR + 2 * f0] = pk;
        } else {
          // t=49: nmt=2 -> only waves 0,1 run; rows jw+r cover exactly [0,32).
          const int di = (j0 + jw + r) * 32 + 2 * f0;
          part = __builtin_fmaf(hv2[0], dws[di],
                 __builtin_fmaf(hv2[1], dws[di + 1], part));
        }
      }
    }
    __syncthreads();
  }

  // ---- reduce fused-dense partials
#pragma unroll
  for (int off = 32; off > 0; off >>= 1) part += __shfl_down(part, off);
  if (lane == 0) atomicAdd(&acc_out[b], part);
}

__global__ void init_acc(float* ws) {
  if (threadIdx.x < 32) ws[threadIdx.x] = 0.0f;
}

__global__ void finalize(const float* __restrict__ ws,
                         const float* __restrict__ db,
                         float* __restrict__ out) {
  int i = threadIdx.x;
  if (i < 32) out[i] = ws[i] + db[0];
}

extern "C" void kernel_launch(void* const* d_in, const int* in_sizes, int n_in,
                              void* d_out, int out_size, void* d_ws, size_t ws_size,
                              hipStream_t stream) {
  const float* x  = (const float*)d_in[0];
  const float* k  = (const float*)d_in[1];
  const float* rk = (const float*)d_in[2];
  const float* bi = (const float*)d_in[3];
  const float* dw = (const float*)d_in[4];
  const float* db = (const float*)d_in[5];
  float* ws = (float*)d_ws;
  float* out = (float*)d_out;

  hipLaunchKernelGGL(init_acc, dim3(1), dim3(64), 0, stream, ws);
  hipLaunchKernelGGL(convlstm_scan, dim3(1024), dim3(256), 0, stream,
                     x, k, rk, bi, dw, ws);
  hipLaunchKernelGGL(finalize, dim3(1), dim3(64), 0, stream, ws, db, out);
}

// Round 8
// 249.485 us; speedup vs baseline: 2.8603x; 2.8603x over previous
//
#include <hip/hip_runtime.h>

// ConvLSTM1D fused scan for MI355X — f32 I/O, bf16 MFMA.
// Round 8: revert to 2 blocks/CU (r7's 4-wave bound spilled everything).
// New: (a) both slots' MFMAs hoisted ahead of both slots' pointwise so the
// matrix-pipe time drains under the VALU-heavy LSTM math (within-wave
// overlap); (b) pointwise done on float2 (p-pair) to get v_pk_* packed f32.
// Halo-tile trick: block owns j-range [j0, j0+64); recurrent conv reads h[j+1]
// only, so a right halo that starts at +49 rows and shrinks by 1 per step makes
// every block's 50-step scan fully independent (no grid sync).

#define TT 50
#define LTILE 64
#define ROWS 129   // 64 owned + 49 halo + 1 read-halo row (row 128 stays 0)
#define HSTR 40    // h row stride (shorts); mult of 8 -> 16B-aligned ds_read_b128

typedef __attribute__((ext_vector_type(8))) short short8;
typedef __attribute__((ext_vector_type(4))) float floatx4;
typedef __attribute__((ext_vector_type(2))) float floatx2;

__device__ __forceinline__ unsigned short f2b_rne(float f) {
  union { float f; unsigned u; } v; v.f = f;
  unsigned r = v.u + 0x7FFFu + ((v.u >> 16) & 1u);
  return (unsigned short)(r >> 16);
}
__device__ __forceinline__ unsigned short f2b_trunc(float f) {
  union { float f; unsigned u; } v; v.f = f;
  return (unsigned short)(v.u >> 16);
}
// packed hard_sigmoid: clamp(0.2x+0.5, 0, 1) — pk_fma + 2 scalar med3
__device__ __forceinline__ floatx2 hsig2(floatx2 x) {
  floatx2 y = x * 0.2f + 0.5f;
  floatx2 r;
  r.x = __builtin_amdgcn_fmed3f(y.x, 0.0f, 1.0f);
  r.y = __builtin_amdgcn_fmed3f(y.y, 0.0f, 1.0f);
  return r;
}
// packed tanh via exp2: pk_mul + 2x v_exp + pk_add + 2x v_rcp + pk_fma
__device__ __forceinline__ floatx2 ftanh2(floatx2 x) {
  const float k = 2.885390082f;   // 2*log2(e)
  floatx2 z = x * k;
  floatx2 e;
  e.x = __builtin_amdgcn_exp2f(z.x);
  e.y = __builtin_amdgcn_exp2f(z.y);
  floatx2 d = e + 1.0f;
  floatx2 r;
  r.x = __builtin_amdgcn_rcpf(d.x);
  r.y = __builtin_amdgcn_rcpf(d.y);
  return 1.0f - 2.0f * r;
}

__global__ __launch_bounds__(256, 2)
void convlstm_scan(const float* __restrict__ xs,   // x [32][50][2048][8] f32
                   const float* __restrict__ ks,   // kernel [2][8][128] f32
                   const float* __restrict__ rks,  // rec_kernel [2][32][128] f32
                   const float* __restrict__ bs,   // bias [128] f32
                   const float* __restrict__ dws,  // dense_w [32768] f32
                   float* __restrict__ acc_out) {  // [32] f32 accumulators
  __shared__ short hbH[2][ROWS * HSTR];   // h (bf16), double-buffered

  const int tid  = threadIdx.x;
  const int b    = blockIdx.x >> 4;
  const int j0   = (blockIdx.x & 15) * LTILE;
  const int wave = tid >> 6;
  const int lane = tid & 63;
  const int q    = lane >> 4;
  const int f0   = lane & 15;

  for (int e = tid; e < ROWS * HSTR; e += 256)
    ((int*)hbH)[e] = 0;

  // ---- B fragments in registers, GATE-PAIR PERMUTED columns:
  // tile n = 2g+p, col f0  <->  oc = g*32 + 2*f0 + p   (g = gate, p = pair)
  // => lane f0's two outputs per row are adjacent h-cols 2f0, 2f0+1.
  short8 Bwh0[8], Bwh1[8], Bxw[8];
#pragma unroll
  for (int n = 0; n < 8; ++n) {
    const int oc = (n >> 1) * 32 + 2 * f0 + (n & 1);
    short8 th;
#pragma unroll
    for (int j = 0; j < 8; ++j)
      th[j] = (short)f2b_rne(rks[(q * 8 + j) * 128 + oc]);
    Bwh0[n] = th;
#pragma unroll
    for (int j = 0; j < 8; ++j)
      th[j] = (short)f2b_rne(rks[(32 + q * 8 + j) * 128 + oc]);
    Bwh1[n] = th;
    // x-conv B: k rows 0..7 = tap0 k_hi, 8..15 = tap1 k_hi (paired with x_hi),
    // row 16 = bias (ax carries 1.0 there), rows 17..31 = 0.
    short8 tx = {0, 0, 0, 0, 0, 0, 0, 0};
    if (q < 2) {
#pragma unroll
      for (int j = 0; j < 8; ++j)
        tx[j] = (short)f2b_rne(ks[(q * 8 + j) * 128 + oc]);
    } else if (q == 2) {
      tx[0] = (short)f2b_rne(bs[oc]);
    }
    Bxw[n] = tx;
  }

  // ax constant part: lane (q=2, elem 0) = bf16 1.0 (bias marker), else 0.
  short8 axc = {0, 0, 0, 0, 0, 0, 0, 0};
  if (q == 2) axc[0] = (short)0x3F80;

  const floatx4 zero4 = {0.0f, 0.0f, 0.0f, 0.0f};

  floatx2 cst[2][4];   // c-state: [slot][r], packed over p-pair
#pragma unroll
  for (int s = 0; s < 2; ++s)
#pragma unroll
    for (int r = 0; r < 4; ++r) { cst[s][r].x = 0.0f; cst[s][r].y = 0.0f; }

  // ---- hoisted x pointers (row clamp is t-invariant); advance 16384 fl/step
  const float* xptr[2];
  floatx4 px0[2], px1[2];
#pragma unroll
  for (int s = 0; s < 2; ++s) {
    const int jr = (wave + 4 * s) * 16 + f0;
    const int jm = min(j0 + jr, 1023);
    xptr[s] = xs + (size_t)b * TT * (2048 * 8) + (size_t)(2 * jm + (q & 1)) * 8;
    px0[s] = *(const floatx4*)xptr[s];
    px1[s] = *(const floatx4*)(xptr[s] + 4);
  }

  const int maxrows = 1024 - j0;
  float part = 0.0f;                        // fused Dense(1) partial
  __syncthreads();

  for (int t = 0; t < TT; ++t) {
    const short* curH = hbH[t & 1];
    short* nxtH = hbH[(t & 1) ^ 1];
    int rows = LTILE + (TT - 1) - t;          // halo shrinks 1/step
    if (rows > maxrows) rows = maxrows;
    const int nmt = (rows + 15) >> 4;         // 4..8; slot0 always live
    const int act1 = (wave + 4) < nmt;        // wave-uniform slot1 guard
    const int last = (t == TT - 1);

    // 1) Front-load a-frag LDS reads (max row read = 7*16+15+1 = 128 = ROWS-1).
    short8 a0h[2], a1h[2];
#pragma unroll
    for (int s = 0; s < 2; ++s) {
      const int jr = (wave + 4 * s) * 16 + f0;
      a0h[s] = *(const short8*)&curH[jr * HSTR + q * 8];
      a1h[s] = *(const short8*)&curH[(jr + 1) * HSTR + q * 8];
    }

    // 2) Build ax (x_hi) from registers prefetched last step.
    short8 ax[2];
#pragma unroll
    for (int s = 0; s < 2; ++s) {
      ax[s] = axc;
      if (q < 2) {
        floatx4 x0 = px0[s], x1 = px1[s];
#pragma unroll
        for (int jj = 0; jj < 4; ++jj) ax[s][jj] = (short)f2b_trunc(x0[jj]);
#pragma unroll
        for (int jj = 0; jj < 4; ++jj) ax[s][4 + jj] = (short)f2b_trunc(x1[jj]);
      }
    }

    // 3) Next-step x prefetch: constant-stride pointer bump (overlaps MFMA).
    if (!last) {
#pragma unroll
      for (int s = 0; s < 2; ++s) {
        xptr[s] += 2048 * 8;
        px0[s] = *(const floatx4*)xptr[s];
        px1[s] = *(const floatx4*)(xptr[s] + 4);
      }
    }

    // 4) ALL MFMAs first (both slots) — matrix pipe drains under pointwise.
    floatx4 acc0[8], acc1[8];
#pragma unroll
    for (int n = 0; n < 8; ++n)
      acc0[n] = __builtin_amdgcn_mfma_f32_16x16x32_bf16(ax[0], Bxw[n], zero4, 0, 0, 0);
#pragma unroll
    for (int n = 0; n < 8; ++n)
      acc0[n] = __builtin_amdgcn_mfma_f32_16x16x32_bf16(a0h[0], Bwh0[n], acc0[n], 0, 0, 0);
#pragma unroll
    for (int n = 0; n < 8; ++n)
      acc0[n] = __builtin_amdgcn_mfma_f32_16x16x32_bf16(a1h[0], Bwh1[n], acc0[n], 0, 0, 0);
    if (act1) {
#pragma unroll
      for (int n = 0; n < 8; ++n)
        acc1[n] = __builtin_amdgcn_mfma_f32_16x16x32_bf16(ax[1], Bxw[n], zero4, 0, 0, 0);
#pragma unroll
      for (int n = 0; n < 8; ++n)
        acc1[n] = __builtin_amdgcn_mfma_f32_16x16x32_bf16(a0h[1], Bwh0[n], acc1[n], 0, 0, 0);
#pragma unroll
      for (int n = 0; n < 8; ++n)
        acc1[n] = __builtin_amdgcn_mfma_f32_16x16x32_bf16(a1h[1], Bwh1[n], acc1[n], 0, 0, 0);
    }

    // 5) Pointwise LSTM (packed over p-pair). D[m-row = q*4+r][tile n, col f0
    //    -> h-col 2f0 + (n&1)]. Gates: zi=acc[0/1], zf=acc[2/3], zc=acc[4/5],
    //    zo=acc[6/7].
#pragma unroll
    for (int s = 0; s < 2; ++s) {
      if (s == 1 && !act1) continue;
      const floatx4* acc = (s == 0) ? acc0 : acc1;
      const int jw = (wave + 4 * s) * 16 + q * 4;
#pragma unroll
      for (int r = 0; r < 4; ++r) {
        floatx2 zi = {acc[0][r], acc[1][r]};
        floatx2 zf = {acc[2][r], acc[3][r]};
        floatx2 zc = {acc[4][r], acc[5][r]};
        floatx2 zo = {acc[6][r], acc[7][r]};
        floatx2 ig = hsig2(zi), fg = hsig2(zf), og = hsig2(zo);
        floatx2 cn = fg * cst[s][r] + ig * ftanh2(zc);
        cst[s][r] = cn;
        floatx2 hv = og * ftanh2(cn);
        if (!last) {
          unsigned pk = (unsigned)f2b_rne(hv.x) |
                        ((unsigned)f2b_rne(hv.y) << 16);
          *(unsigned*)&nxtH[(jw + r) * HSTR + 2 * f0] = pk;
        } else {
          // t=49: nmt=4 -> slot0 only; rows jw+r cover exactly [0,64).
          const int di = (j0 + jw + r) * 32 + 2 * f0;
          part = __builtin_fmaf(hv.x, dws[di],
                 __builtin_fmaf(hv.y, dws[di + 1], part));
        }
      }
    }
    __syncthreads();
  }

  // ---- reduce fused-dense partials
#pragma unroll
  for (int off = 32; off > 0; off >>= 1) part += __shfl_down(part, off);
  if (lane == 0) atomicAdd(&acc_out[b], part);
}

__global__ void init_acc(float* ws) {
  if (threadIdx.x < 32) ws[threadIdx.x] = 0.0f;
}

__global__ void finalize(const float* __restrict__ ws,
                         const float* __restrict__ db,
                         float* __restrict__ out) {
  int i = threadIdx.x;
  if (i < 32) out[i] = ws[i] + db[0];
}

extern "C" void kernel_launch(void* const* d_in, const int* in_sizes, int n_in,
                              void* d_out, int out_size, void* d_ws, size_t ws_size,
                              hipStream_t stream) {
  const float* x  = (const float*)d_in[0];
  const float* k  = (const float*)d_in[1];
  const float* rk = (const float*)d_in[2];
  const float* bi = (const float*)d_in[3];
  const float* dw = (const float*)d_in[4];
  const float* db = (const float*)d_in[5];
  float* ws = (float*)d_ws;
  float* out = (float*)d_out;

  hipLaunchKernelGGL(init_acc, dim3(1), dim3(64), 0, stream, ws);
  hipLaunchKernelGGL(convlstm_scan, dim3(512), dim3(256), 0, stream,
                     x, k, rk, bi, dw, ws);
  hipLaunchKernelGGL(finalize, dim3(1), dim3(64), 0, stream, ws, db, out);
}